// Round 3
// baseline (3085.099 us; speedup 1.0000x reference)
//
#include <hip/hip_runtime.h>
#include <cstdint>
#include <cstddef>

#define N_NODES 8192
#define N_EDGES 131072
#define F_IN    512
#define H1C     32
#define H2C     16

// ---------------- helpers ----------------

__device__ __forceinline__ float block_reduce_sum(float v, int nthreads) {
    #pragma unroll
    for (int off = 32; off; off >>= 1) v += __shfl_down(v, off, 64);
    __shared__ float sred[16];
    int lane = threadIdx.x & 63, wid = threadIdx.x >> 6;
    if (lane == 0) sred[wid] = v;
    __syncthreads();
    float s = 0.0f;
    if (threadIdx.x == 0) {
        int nw = nthreads >> 6;
        for (int i = 0; i < nw; ++i) s += sred[i];
    }
    return s;
}

__device__ __forceinline__ float bce_elem(float l, int y) {
    // y=1: 10*softplus(-l); y=0: softplus(l).  lse = log(1+exp(-|l|))
    float lse = __logf(1.0f + __expf(-fabsf(l)));
    return y ? 10.0f * (lse + fmaxf(-l, 0.0f)) : (lse + fmaxf(l, 0.0f));
}

// ---------------- kernels ----------------

__global__ void k_deg(const int* __restrict__ dst, int* __restrict__ deg) {
    int e = blockIdx.x * 256 + threadIdx.x;
    if (e < N_EDGES) atomicAdd(&deg[dst[e]], 1);
}

__global__ void k_dinv(const int* __restrict__ deg, float* __restrict__ dinv) {
    int i = blockIdx.x * 256 + threadIdx.x;
    dinv[i] = rsqrtf((float)deg[i] + 1.0f);
}

// h = x @ W1 : [8192,512] x [512,32], 128-row tiles
__global__ void k_gemm1(const float* __restrict__ x, const float* __restrict__ W1,
                        float* __restrict__ h) {
    __shared__ float xs[128][33];
    __shared__ float wsm[32][32];
    int tid = threadIdx.x;
    int tc = tid & 7;
    int tr = tid >> 3;
    int rowbase = blockIdx.x * 128;

    float accx[4], accy[4], accz[4], accw[4];
    #pragma unroll
    for (int i = 0; i < 4; ++i) { accx[i]=0.f; accy[i]=0.f; accz[i]=0.f; accw[i]=0.f; }

    for (int kc = 0; kc < F_IN / 32; ++kc) {
        __syncthreads();
        #pragma unroll
        for (int it = 0; it < 4; ++it) {
            int f = tid + it * 256;
            int r = f >> 3, pos = (f & 7) << 2;
            float4 v = *(const float4*)&x[(size_t)(rowbase + r) * F_IN + kc * 32 + pos];
            xs[r][pos + 0] = v.x; xs[r][pos + 1] = v.y;
            xs[r][pos + 2] = v.z; xs[r][pos + 3] = v.w;
        }
        {
            int k = tid >> 3, pos = (tid & 7) << 2;
            *(float4*)&wsm[k][pos] = *(const float4*)&W1[(size_t)(kc * 32 + k) * H1C + pos];
        }
        __syncthreads();
        #pragma unroll
        for (int k = 0; k < 32; ++k) {
            float4 wv = *(const float4*)&wsm[k][tc << 2];
            float x0 = xs[tr][k], x1 = xs[tr + 32][k], x2 = xs[tr + 64][k], x3 = xs[tr + 96][k];
            accx[0] += x0 * wv.x; accy[0] += x0 * wv.y; accz[0] += x0 * wv.z; accw[0] += x0 * wv.w;
            accx[1] += x1 * wv.x; accy[1] += x1 * wv.y; accz[1] += x1 * wv.z; accw[1] += x1 * wv.w;
            accx[2] += x2 * wv.x; accy[2] += x2 * wv.y; accz[2] += x2 * wv.z; accw[2] += x2 * wv.w;
            accx[3] += x3 * wv.x; accy[3] += x3 * wv.y; accz[3] += x3 * wv.z; accw[3] += x3 * wv.w;
        }
    }
    #pragma unroll
    for (int i = 0; i < 4; ++i) {
        float4 v; v.x = accx[i]; v.y = accy[i]; v.z = accz[i]; v.w = accw[i];
        *(float4*)&h[(size_t)(rowbase + tr + 32 * i) * H1C + (tc << 2)] = v;
    }
}

__global__ void k_scatter1(const int* __restrict__ src, const int* __restrict__ dst,
                           const float* __restrict__ h, const float* __restrict__ dinv,
                           float* __restrict__ agg1) {
    int gid = blockIdx.x * 256 + threadIdx.x;
    int e = gid >> 5, f = gid & 31;
    int s = src[e], d = dst[e];
    float c = dinv[s] * dinv[d];
    unsafeAtomicAdd(&agg1[(d << 5) + f], h[(s << 5) + f] * c);
}

__global__ void k_h1(const float* __restrict__ agg1, const float* __restrict__ h,
                     const float* __restrict__ dinv, float* __restrict__ h1) {
    int i4 = blockIdx.x * 256 + threadIdx.x;
    int row = i4 >> 3;
    float di = dinv[row], d2 = di * di;
    float4 a = ((const float4*)agg1)[i4];
    float4 hv = ((const float4*)h)[i4];
    float4 r;
    r.x = fmaxf(a.x + hv.x * d2, 0.0f);
    r.y = fmaxf(a.y + hv.y * d2, 0.0f);
    r.z = fmaxf(a.z + hv.z * d2, 0.0f);
    r.w = fmaxf(a.w + hv.w * d2, 0.0f);
    ((float4*)h1)[i4] = r;
}

__global__ void k_gemm2(const float* __restrict__ h1, const float* __restrict__ W2,
                        const float* __restrict__ W3, float* __restrict__ h2mu,
                        float* __restrict__ h2lv) {
    __shared__ float w2s[H1C * H2C], w3s[H1C * H2C];
    int tid = threadIdx.x;
    for (int i = tid; i < H1C * H2C; i += 256) { w2s[i] = W2[i]; w3s[i] = W3[i]; }
    __syncthreads();
    int gid = blockIdx.x * 256 + tid;
    int row = gid >> 5, c = gid & 31, col = c & 15;
    const float* wsrc = (c & 16) ? w3s : w2s;
    const float* hr = &h1[(size_t)row << 5];
    float acc = 0.0f;
    #pragma unroll
    for (int k = 0; k < H1C; ++k) acc += hr[k] * wsrc[(k << 4) + col];
    if (c & 16) h2lv[(row << 4) + col] = acc;
    else        h2mu[(row << 4) + col] = acc;
}

__global__ void k_scatter2(const int* __restrict__ src, const int* __restrict__ dst,
                           const float* __restrict__ h2mu, const float* __restrict__ h2lv,
                           const float* __restrict__ dinv, float* __restrict__ aggmu,
                           float* __restrict__ agglv) {
    int gid = blockIdx.x * 256 + threadIdx.x;
    int e = gid >> 5, f = gid & 31;
    int s = src[e], d = dst[e];
    float c = dinv[s] * dinv[d];
    int ff = f & 15;
    if (f < 16) unsafeAtomicAdd(&aggmu[(d << 4) + ff], h2mu[(s << 4) + ff] * c);
    else        unsafeAtomicAdd(&agglv[(d << 4) + ff], h2lv[(s << 4) + ff] * c);
}

__global__ void k_zmu(const float* __restrict__ aggmu, const float* __restrict__ agglv,
                      const float* __restrict__ h2mu, const float* __restrict__ h2lv,
                      const float* __restrict__ dinv, const float* __restrict__ eps,
                      float* __restrict__ zbuf, float* __restrict__ out,
                      float* __restrict__ kldp) {
    int gid = blockIdx.x * 256 + threadIdx.x;
    int row = gid >> 4;
    float di = dinv[row], d2 = di * di;
    float m  = aggmu[gid] + h2mu[gid] * d2;
    float lv = agglv[gid] + h2lv[gid] * d2;
    float el = __expf(lv);
    float zv = eps[gid] * el + m;
    zbuf[gid] = zv;
    out[1 + gid] = m;
    float kt = 1.0f + 2.0f * lv - m * m - el * el;
    float bs = block_reduce_sum(kt, 256);
    if (threadIdx.x == 0) kldp[blockIdx.x] = bs;
}

// BCE over a 64(row) x 128(col) logits tile per block; 512 threads, 4 blocks/CU.
// adj loaded with PLAIN cached int4 loads, issued after the staging barrier so
// the ~32KB/block stream stays in flight under the FMA loop (never drained by
// a barrier). No packing, no nontemporal.
__global__ void __launch_bounds__(512, 8)
k_bce(const float* __restrict__ z, const int* __restrict__ adj,
      float* __restrict__ part) {
    __shared__ float zrT[16][68];    // 64 rows, transposed, padded
    __shared__ float zcT[16][132];   // 128 cols, transposed, padded
    int tid = threadIdx.x;
    int rbase = blockIdx.y << 6, cbase = blockIdx.x << 7;

    // stage z tiles (transposed): zc = 512 float4 (all threads), zr = 256 (half)
    {
        int r = tid >> 2, kc = (tid & 3) << 2;
        float4 w = *(const float4*)&z[(size_t)(cbase + r) * H2C + kc];
        zcT[kc + 0][r] = w.x; zcT[kc + 1][r] = w.y; zcT[kc + 2][r] = w.z; zcT[kc + 3][r] = w.w;
        if (tid < 256) {
            float4 v = *(const float4*)&z[(size_t)(rbase + r) * H2C + kc];
            zrT[kc + 0][r] = v.x; zrT[kc + 1][r] = v.y; zrT[kc + 2][r] = v.z; zrT[kc + 3][r] = v.w;
        }
    }
    __syncthreads();

    int tx = tid & 31, ty = tid >> 5;   // 32 col-groups x 16 row-groups, 4x4 each

    // adjacency: 4 x int4, plain cached loads, in flight during the FMA loop
    const int* arow = adj + (size_t)(rbase + (ty << 2)) * N_NODES + cbase + (tx << 2);
    int4 y0 = *(const int4*)(arow);
    int4 y1 = *(const int4*)(arow + N_NODES);
    int4 y2 = *(const int4*)(arow + 2 * N_NODES);
    int4 y3 = *(const int4*)(arow + 3 * N_NODES);

    float a0x=0,a0y=0,a0z=0,a0w=0, a1x=0,a1y=0,a1z=0,a1w=0;
    float a2x=0,a2y=0,a2z=0,a2w=0, a3x=0,a3y=0,a3z=0,a3w=0;
    #pragma unroll
    for (int k = 0; k < H2C; ++k) {
        float4 av = *(const float4*)&zrT[k][ty << 2];
        float4 ac = *(const float4*)&zcT[k][tx << 2];
        a0x += av.x * ac.x; a0y += av.x * ac.y; a0z += av.x * ac.z; a0w += av.x * ac.w;
        a1x += av.y * ac.x; a1y += av.y * ac.y; a1z += av.y * ac.z; a1w += av.y * ac.w;
        a2x += av.z * ac.x; a2y += av.z * ac.y; a2z += av.z * ac.z; a2w += av.z * ac.w;
        a3x += av.w * ac.x; a3y += av.w * ac.y; a3z += av.w * ac.z; a3w += av.w * ac.w;
    }
    float lsum = 0.0f;
    lsum += bce_elem(a0x, y0.x) + bce_elem(a0y, y0.y) + bce_elem(a0z, y0.z) + bce_elem(a0w, y0.w);
    lsum += bce_elem(a1x, y1.x) + bce_elem(a1y, y1.y) + bce_elem(a1z, y1.z) + bce_elem(a1w, y1.w);
    lsum += bce_elem(a2x, y2.x) + bce_elem(a2y, y2.y) + bce_elem(a2z, y2.z) + bce_elem(a2w, y2.w);
    lsum += bce_elem(a3x, y3.x) + bce_elem(a3y, y3.y) + bce_elem(a3z, y3.z) + bce_elem(a3w, y3.w);

    float bs = block_reduce_sum(lsum, 512);
    if (tid == 0) part[blockIdx.y * gridDim.x + blockIdx.x] = bs;
}

__global__ void k_final(const float* __restrict__ part, const float* __restrict__ kldp,
                        const float* __restrict__ norm, float* __restrict__ out) {
    double s = 0.0, k = 0.0;
    for (int i = threadIdx.x; i < 8192; i += 256) s += (double)part[i];
    for (int i = threadIdx.x; i < 512; i += 256) k += (double)kldp[i];
    #pragma unroll
    for (int off = 32; off; off >>= 1) {
        s += __shfl_down(s, off, 64);
        k += __shfl_down(k, off, 64);
    }
    __shared__ double ss[4], kk[4];
    int lane = threadIdx.x & 63, wid = threadIdx.x >> 6;
    if (lane == 0) { ss[wid] = s; kk[wid] = k; }
    __syncthreads();
    if (threadIdx.x == 0) {
        double st = ss[0] + ss[1] + ss[2] + ss[3];
        double kt = kk[0] + kk[1] + kk[2] + kk[3];
        double bce = st / ((double)N_NODES * (double)N_NODES);
        double kld = (-0.5 / (double)N_NODES) * (kt / (double)N_NODES);
        out[0] = (float)((double)norm[0] * bce + kld);
    }
}

// ---------------- launch ----------------

extern "C" void kernel_launch(void* const* d_in, const int* in_sizes, int n_in,
                              void* d_out, int out_size, void* d_ws, size_t ws_size,
                              hipStream_t stream) {
    const float* x    = (const float*)d_in[0];
    const int*   ei   = (const int*)d_in[1];
    const int*   adj  = (const int*)d_in[2];
    const float* eps  = (const float*)d_in[3];
    const float* norm = (const float*)d_in[4];
    const float* W1   = (const float*)d_in[5];
    const float* W2   = (const float*)d_in[6];
    const float* W3   = (const float*)d_in[7];
    float* out = (float*)d_out;
    char*  ws  = (char*)d_ws;

    const int* src = ei;
    const int* dst = ei + N_EDGES;

    int*   deg    = (int*)  (ws + 0);
    float* dinv   = (float*)(ws + 32768);
    float* h      = (float*)(ws + 65536);
    float* agg1   = (float*)(ws + 1114112);
    float* h1     = (float*)(ws + 2162688);
    float* h2mu   = (float*)(ws + 3211264);
    float* h2lv   = (float*)(ws + 3735552);
    float* aggmu  = (float*)(ws + 4259840);
    float* agglv  = (float*)(ws + 4784128);
    float* zbuf   = (float*)(ws + 5308416);
    float* part   = (float*)(ws + 5832704);   // 8192 f32
    float* kldp   = (float*)(ws + 5898240);   // 512 f32

    hipMemsetAsync(deg, 0, 32768, stream);
    hipMemsetAsync(agg1, 0, 1048576, stream);
    hipMemsetAsync(aggmu, 0, 1048576, stream);  // covers agglv too

    k_deg<<<N_EDGES / 256, 256, 0, stream>>>(dst, deg);
    k_dinv<<<N_NODES / 256, 256, 0, stream>>>(deg, dinv);
    k_gemm1<<<N_NODES / 128, 256, 0, stream>>>(x, W1, h);
    k_scatter1<<<(N_EDGES * 32) / 256, 256, 0, stream>>>(src, dst, h, dinv, agg1);
    k_h1<<<(N_NODES * H1C / 4) / 256, 256, 0, stream>>>(agg1, h, dinv, h1);
    k_gemm2<<<(N_NODES * 32) / 256, 256, 0, stream>>>(h1, W2, W3, h2mu, h2lv);
    k_scatter2<<<(N_EDGES * 32) / 256, 256, 0, stream>>>(src, dst, h2mu, h2lv, dinv, aggmu, agglv);
    k_zmu<<<(N_NODES * H2C) / 256, 256, 0, stream>>>(aggmu, agglv, h2mu, h2lv, dinv, eps, zbuf, out, kldp);
    k_bce<<<dim3(64, 128), 512, 0, stream>>>(zbuf, adj, part);
    k_final<<<1, 256, 0, stream>>>(part, kldp, norm, out);
}

// Round 4
// 218.531 us; speedup vs baseline: 14.1174x; 14.1174x over previous
//
#include <hip/hip_runtime.h>
#include <cstdint>
#include <cstddef>

#define N_NODES 8192
#define N_EDGES 131072
#define F_IN    512
#define H1C     32
#define H2C     16

// ---------------- helpers ----------------

__device__ __forceinline__ float block_reduce_sum(float v, int nthreads) {
    #pragma unroll
    for (int off = 32; off; off >>= 1) v += __shfl_down(v, off, 64);
    __shared__ float sred[16];
    int lane = threadIdx.x & 63, wid = threadIdx.x >> 6;
    if (lane == 0) sred[wid] = v;
    __syncthreads();
    float s = 0.0f;
    if (threadIdx.x == 0) {
        int nw = nthreads >> 6;
        for (int i = 0; i < nw; ++i) s += sred[i];
    }
    return s;
}

__device__ __forceinline__ float bce_elem(float l, int y) {
    // y=1: 10*softplus(-l); y=0: softplus(l).  lse = log(1+exp(-|l|))
    float lse = __logf(1.0f + __expf(-fabsf(l)));
    return y ? 10.0f * (lse + fmaxf(-l, 0.0f)) : (lse + fmaxf(l, 0.0f));
}

// ---------------- kernels ----------------

__global__ void k_deg(const int* __restrict__ dst, int* __restrict__ deg) {
    int e = blockIdx.x * 256 + threadIdx.x;
    if (e < N_EDGES) atomicAdd(&deg[dst[e]], 1);
}

__global__ void k_dinv(const int* __restrict__ deg, float* __restrict__ dinv) {
    int i = blockIdx.x * 256 + threadIdx.x;
    dinv[i] = rsqrtf((float)deg[i] + 1.0f);
}

// h = x @ W1 : [8192,512] x [512,32], 128-row tiles
__global__ void k_gemm1(const float* __restrict__ x, const float* __restrict__ W1,
                        float* __restrict__ h) {
    __shared__ float xs[128][33];
    __shared__ float wsm[32][32];
    int tid = threadIdx.x;
    int tc = tid & 7;
    int tr = tid >> 3;
    int rowbase = blockIdx.x * 128;

    float accx[4], accy[4], accz[4], accw[4];
    #pragma unroll
    for (int i = 0; i < 4; ++i) { accx[i]=0.f; accy[i]=0.f; accz[i]=0.f; accw[i]=0.f; }

    for (int kc = 0; kc < F_IN / 32; ++kc) {
        __syncthreads();
        #pragma unroll
        for (int it = 0; it < 4; ++it) {
            int f = tid + it * 256;
            int r = f >> 3, pos = (f & 7) << 2;
            float4 v = *(const float4*)&x[(size_t)(rowbase + r) * F_IN + kc * 32 + pos];
            xs[r][pos + 0] = v.x; xs[r][pos + 1] = v.y;
            xs[r][pos + 2] = v.z; xs[r][pos + 3] = v.w;
        }
        {
            int k = tid >> 3, pos = (tid & 7) << 2;
            *(float4*)&wsm[k][pos] = *(const float4*)&W1[(size_t)(kc * 32 + k) * H1C + pos];
        }
        __syncthreads();
        #pragma unroll
        for (int k = 0; k < 32; ++k) {
            float4 wv = *(const float4*)&wsm[k][tc << 2];
            float x0 = xs[tr][k], x1 = xs[tr + 32][k], x2 = xs[tr + 64][k], x3 = xs[tr + 96][k];
            accx[0] += x0 * wv.x; accy[0] += x0 * wv.y; accz[0] += x0 * wv.z; accw[0] += x0 * wv.w;
            accx[1] += x1 * wv.x; accy[1] += x1 * wv.y; accz[1] += x1 * wv.z; accw[1] += x1 * wv.w;
            accx[2] += x2 * wv.x; accy[2] += x2 * wv.y; accz[2] += x2 * wv.z; accw[2] += x2 * wv.w;
            accx[3] += x3 * wv.x; accy[3] += x3 * wv.y; accz[3] += x3 * wv.z; accw[3] += x3 * wv.w;
        }
    }
    #pragma unroll
    for (int i = 0; i < 4; ++i) {
        float4 v; v.x = accx[i]; v.y = accy[i]; v.z = accz[i]; v.w = accw[i];
        *(float4*)&h[(size_t)(rowbase + tr + 32 * i) * H1C + (tc << 2)] = v;
    }
}

__global__ void k_scatter1(const int* __restrict__ src, const int* __restrict__ dst,
                           const float* __restrict__ h, const float* __restrict__ dinv,
                           float* __restrict__ agg1) {
    int gid = blockIdx.x * 256 + threadIdx.x;
    int e = gid >> 5, f = gid & 31;
    int s = src[e], d = dst[e];
    float c = dinv[s] * dinv[d];
    unsafeAtomicAdd(&agg1[(d << 5) + f], h[(s << 5) + f] * c);
}

__global__ void k_h1(const float* __restrict__ agg1, const float* __restrict__ h,
                     const float* __restrict__ dinv, float* __restrict__ h1) {
    int i4 = blockIdx.x * 256 + threadIdx.x;
    int row = i4 >> 3;
    float di = dinv[row], d2 = di * di;
    float4 a = ((const float4*)agg1)[i4];
    float4 hv = ((const float4*)h)[i4];
    float4 r;
    r.x = fmaxf(a.x + hv.x * d2, 0.0f);
    r.y = fmaxf(a.y + hv.y * d2, 0.0f);
    r.z = fmaxf(a.z + hv.z * d2, 0.0f);
    r.w = fmaxf(a.w + hv.w * d2, 0.0f);
    ((float4*)h1)[i4] = r;
}

__global__ void k_gemm2(const float* __restrict__ h1, const float* __restrict__ W2,
                        const float* __restrict__ W3, float* __restrict__ h2mu,
                        float* __restrict__ h2lv) {
    __shared__ float w2s[H1C * H2C], w3s[H1C * H2C];
    int tid = threadIdx.x;
    for (int i = tid; i < H1C * H2C; i += 256) { w2s[i] = W2[i]; w3s[i] = W3[i]; }
    __syncthreads();
    int gid = blockIdx.x * 256 + tid;
    int row = gid >> 5, c = gid & 31, col = c & 15;
    const float* wsrc = (c & 16) ? w3s : w2s;
    const float* hr = &h1[(size_t)row << 5];
    float acc = 0.0f;
    #pragma unroll
    for (int k = 0; k < H1C; ++k) acc += hr[k] * wsrc[(k << 4) + col];
    if (c & 16) h2lv[(row << 4) + col] = acc;
    else        h2mu[(row << 4) + col] = acc;
}

__global__ void k_scatter2(const int* __restrict__ src, const int* __restrict__ dst,
                           const float* __restrict__ h2mu, const float* __restrict__ h2lv,
                           const float* __restrict__ dinv, float* __restrict__ aggmu,
                           float* __restrict__ agglv) {
    int gid = blockIdx.x * 256 + threadIdx.x;
    int e = gid >> 5, f = gid & 31;
    int s = src[e], d = dst[e];
    float c = dinv[s] * dinv[d];
    int ff = f & 15;
    if (f < 16) unsafeAtomicAdd(&aggmu[(d << 4) + ff], h2mu[(s << 4) + ff] * c);
    else        unsafeAtomicAdd(&agglv[(d << 4) + ff], h2lv[(s << 4) + ff] * c);
}

__global__ void k_zmu(const float* __restrict__ aggmu, const float* __restrict__ agglv,
                      const float* __restrict__ h2mu, const float* __restrict__ h2lv,
                      const float* __restrict__ dinv, const float* __restrict__ eps,
                      float* __restrict__ zbuf, float* __restrict__ out,
                      float* __restrict__ kldp) {
    int gid = blockIdx.x * 256 + threadIdx.x;
    int row = gid >> 4;
    float di = dinv[row], d2 = di * di;
    float m  = aggmu[gid] + h2mu[gid] * d2;
    float lv = agglv[gid] + h2lv[gid] * d2;
    float el = __expf(lv);
    float zv = eps[gid] * el + m;
    zbuf[gid] = zv;
    out[1 + gid] = m;
    float kt = 1.0f + 2.0f * lv - m * m - el * el;
    float bs = block_reduce_sum(kt, 256);
    if (threadIdx.x == 0) kldp[blockIdx.x] = bs;
}

// BCE over a 64(row) x 128(col) logits tile per block; 512 threads.
// NOTE: no min-waves in launch_bounds — round 3's (512,8) capped VGPRs at 32
// and spilled everything to scratch (FETCH 10.4 GB, 6x slowdown). Let the
// compiler take ~64 VGPRs; occupancy 8 waves/SIMD is still available.
__global__ void __launch_bounds__(512)
k_bce(const float* __restrict__ z, const int* __restrict__ adj,
      float* __restrict__ part) {
    __shared__ float zrT[16][68];    // 64 rows, transposed, padded
    __shared__ float zcT[16][132];   // 128 cols, transposed, padded
    int tid = threadIdx.x;
    int rbase = blockIdx.y << 6, cbase = blockIdx.x << 7;

    // stage z tiles (transposed): zc = 512 float4 (all threads), zr = 256 (half)
    {
        int r = tid >> 2, kc = (tid & 3) << 2;
        float4 w = *(const float4*)&z[(size_t)(cbase + r) * H2C + kc];
        zcT[kc + 0][r] = w.x; zcT[kc + 1][r] = w.y; zcT[kc + 2][r] = w.z; zcT[kc + 3][r] = w.w;
        if (tid < 256) {
            float4 v = *(const float4*)&z[(size_t)(rbase + r) * H2C + kc];
            zrT[kc + 0][r] = v.x; zrT[kc + 1][r] = v.y; zrT[kc + 2][r] = v.z; zrT[kc + 3][r] = v.w;
        }
    }
    __syncthreads();

    int tx = tid & 31, ty = tid >> 5;   // 32 col-groups x 16 row-groups, 4x4 each

    // adjacency: 4 x int4, plain cached loads, in flight during the FMA loop
    const int* arow = adj + (size_t)(rbase + (ty << 2)) * N_NODES + cbase + (tx << 2);
    int4 y0 = *(const int4*)(arow);
    int4 y1 = *(const int4*)(arow + N_NODES);
    int4 y2 = *(const int4*)(arow + 2 * N_NODES);
    int4 y3 = *(const int4*)(arow + 3 * N_NODES);

    float a0x=0,a0y=0,a0z=0,a0w=0, a1x=0,a1y=0,a1z=0,a1w=0;
    float a2x=0,a2y=0,a2z=0,a2w=0, a3x=0,a3y=0,a3z=0,a3w=0;
    #pragma unroll
    for (int k = 0; k < H2C; ++k) {
        float4 av = *(const float4*)&zrT[k][ty << 2];
        float4 ac = *(const float4*)&zcT[k][tx << 2];
        a0x += av.x * ac.x; a0y += av.x * ac.y; a0z += av.x * ac.z; a0w += av.x * ac.w;
        a1x += av.y * ac.x; a1y += av.y * ac.y; a1z += av.y * ac.z; a1w += av.y * ac.w;
        a2x += av.z * ac.x; a2y += av.z * ac.y; a2z += av.z * ac.z; a2w += av.z * ac.w;
        a3x += av.w * ac.x; a3y += av.w * ac.y; a3z += av.w * ac.z; a3w += av.w * ac.w;
    }
    float lsum = 0.0f;
    lsum += bce_elem(a0x, y0.x) + bce_elem(a0y, y0.y) + bce_elem(a0z, y0.z) + bce_elem(a0w, y0.w);
    lsum += bce_elem(a1x, y1.x) + bce_elem(a1y, y1.y) + bce_elem(a1z, y1.z) + bce_elem(a1w, y1.w);
    lsum += bce_elem(a2x, y2.x) + bce_elem(a2y, y2.y) + bce_elem(a2z, y2.z) + bce_elem(a2w, y2.w);
    lsum += bce_elem(a3x, y3.x) + bce_elem(a3y, y3.y) + bce_elem(a3z, y3.z) + bce_elem(a3w, y3.w);

    float bs = block_reduce_sum(lsum, 512);
    if (tid == 0) part[blockIdx.y * gridDim.x + blockIdx.x] = bs;
}

__global__ void k_final(const float* __restrict__ part, const float* __restrict__ kldp,
                        const float* __restrict__ norm, float* __restrict__ out) {
    double s = 0.0, k = 0.0;
    for (int i = threadIdx.x; i < 8192; i += 256) s += (double)part[i];
    for (int i = threadIdx.x; i < 512; i += 256) k += (double)kldp[i];
    #pragma unroll
    for (int off = 32; off; off >>= 1) {
        s += __shfl_down(s, off, 64);
        k += __shfl_down(k, off, 64);
    }
    __shared__ double ss[4], kk[4];
    int lane = threadIdx.x & 63, wid = threadIdx.x >> 6;
    if (lane == 0) { ss[wid] = s; kk[wid] = k; }
    __syncthreads();
    if (threadIdx.x == 0) {
        double st = ss[0] + ss[1] + ss[2] + ss[3];
        double kt = kk[0] + kk[1] + kk[2] + kk[3];
        double bce = st / ((double)N_NODES * (double)N_NODES);
        double kld = (-0.5 / (double)N_NODES) * (kt / (double)N_NODES);
        out[0] = (float)((double)norm[0] * bce + kld);
    }
}

// ---------------- launch ----------------

extern "C" void kernel_launch(void* const* d_in, const int* in_sizes, int n_in,
                              void* d_out, int out_size, void* d_ws, size_t ws_size,
                              hipStream_t stream) {
    const float* x    = (const float*)d_in[0];
    const int*   ei   = (const int*)d_in[1];
    const int*   adj  = (const int*)d_in[2];
    const float* eps  = (const float*)d_in[3];
    const float* norm = (const float*)d_in[4];
    const float* W1   = (const float*)d_in[5];
    const float* W2   = (const float*)d_in[6];
    const float* W3   = (const float*)d_in[7];
    float* out = (float*)d_out;
    char*  ws  = (char*)d_ws;

    const int* src = ei;
    const int* dst = ei + N_EDGES;

    int*   deg    = (int*)  (ws + 0);
    float* dinv   = (float*)(ws + 32768);
    float* h      = (float*)(ws + 65536);
    float* agg1   = (float*)(ws + 1114112);
    float* h1     = (float*)(ws + 2162688);
    float* h2mu   = (float*)(ws + 3211264);
    float* h2lv   = (float*)(ws + 3735552);
    float* aggmu  = (float*)(ws + 4259840);
    float* agglv  = (float*)(ws + 4784128);
    float* zbuf   = (float*)(ws + 5308416);
    float* part   = (float*)(ws + 5832704);   // 8192 f32
    float* kldp   = (float*)(ws + 5898240);   // 512 f32

    hipMemsetAsync(deg, 0, 32768, stream);
    hipMemsetAsync(agg1, 0, 1048576, stream);
    hipMemsetAsync(aggmu, 0, 1048576, stream);  // covers agglv too

    k_deg<<<N_EDGES / 256, 256, 0, stream>>>(dst, deg);
    k_dinv<<<N_NODES / 256, 256, 0, stream>>>(deg, dinv);
    k_gemm1<<<N_NODES / 128, 256, 0, stream>>>(x, W1, h);
    k_scatter1<<<(N_EDGES * 32) / 256, 256, 0, stream>>>(src, dst, h, dinv, agg1);
    k_h1<<<(N_NODES * H1C / 4) / 256, 256, 0, stream>>>(agg1, h, dinv, h1);
    k_gemm2<<<(N_NODES * 32) / 256, 256, 0, stream>>>(h1, W2, W3, h2mu, h2lv);
    k_scatter2<<<(N_EDGES * 32) / 256, 256, 0, stream>>>(src, dst, h2mu, h2lv, dinv, aggmu, agglv);
    k_zmu<<<(N_NODES * H2C) / 256, 256, 0, stream>>>(aggmu, agglv, h2mu, h2lv, dinv, eps, zbuf, out, kldp);
    k_bce<<<dim3(64, 128), 512, 0, stream>>>(zbuf, adj, part);
    k_final<<<1, 256, 0, stream>>>(part, kldp, norm, out);
}

// Round 5
// 177.727 us; speedup vs baseline: 17.3586x; 1.2296x over previous
//
#include <hip/hip_runtime.h>
#include <cstdint>
#include <cstddef>

#define N_NODES 8192
#define N_EDGES 131072
#define F_IN    512
#define H1C     32
#define H2C     16
#define BCE_NITER 4

// ---------------- helpers ----------------

__device__ __forceinline__ float block_reduce_sum(float v, int nthreads) {
    #pragma unroll
    for (int off = 32; off; off >>= 1) v += __shfl_down(v, off, 64);
    __shared__ float sred[16];
    int lane = threadIdx.x & 63, wid = threadIdx.x >> 6;
    if (lane == 0) sred[wid] = v;
    __syncthreads();
    float s = 0.0f;
    if (threadIdx.x == 0) {
        int nw = nthreads >> 6;
        for (int i = 0; i < nw; ++i) s += sred[i];
    }
    return s;
}

// POS_WEIGHT=10: y=1 -> 10*softplus(-l); y=0 -> softplus(l).
// Branch-free: sp(l) = lse + relu(l), sp(-l) = sp(l) - l
//   val = sp(l)*(1+9y) - 10*y*l
__device__ __forceinline__ float bce_elem(float l, int y) {
    float lse = __logf(1.0f + __expf(-fabsf(l)));
    float sp  = lse + fmaxf(l, 0.0f);
    float w   = (float)y;
    return fmaf(sp, fmaf(9.0f, w, 1.0f), -10.0f * w * l);
}

// ---------------- kernels ----------------

// zero deg (2048 f4) + agg1 (65536 f4) + aggmu/agglv (65536 f4, contiguous)
__global__ void k_init(float4* __restrict__ deg4, float4* __restrict__ agg14,
                       float4* __restrict__ aggmu4) {
    int gid = blockIdx.x * 256 + threadIdx.x;
    float4 zz = {0.0f, 0.0f, 0.0f, 0.0f};
    if (gid < 2048) deg4[gid] = zz;
    else if (gid < 2048 + 65536) agg14[gid - 2048] = zz;
    else aggmu4[gid - 67584] = zz;
}

__global__ void k_deg(const int* __restrict__ dst, int* __restrict__ deg) {
    int e = blockIdx.x * 256 + threadIdx.x;
    if (e < N_EDGES) atomicAdd(&deg[dst[e]], 1);
}

__global__ void k_dinv(const int* __restrict__ deg, float* __restrict__ dinv) {
    int i = blockIdx.x * 256 + threadIdx.x;
    dinv[i] = rsqrtf((float)deg[i] + 1.0f);
}

// h = x @ W1 : [8192,512] x [512,32], 128-row tiles
__global__ void k_gemm1(const float* __restrict__ x, const float* __restrict__ W1,
                        float* __restrict__ h) {
    __shared__ float xs[128][33];
    __shared__ float wsm[32][32];
    int tid = threadIdx.x;
    int tc = tid & 7;
    int tr = tid >> 3;
    int rowbase = blockIdx.x * 128;

    float accx[4], accy[4], accz[4], accw[4];
    #pragma unroll
    for (int i = 0; i < 4; ++i) { accx[i]=0.f; accy[i]=0.f; accz[i]=0.f; accw[i]=0.f; }

    for (int kc = 0; kc < F_IN / 32; ++kc) {
        __syncthreads();
        #pragma unroll
        for (int it = 0; it < 4; ++it) {
            int f = tid + it * 256;
            int r = f >> 3, pos = (f & 7) << 2;
            float4 v = *(const float4*)&x[(size_t)(rowbase + r) * F_IN + kc * 32 + pos];
            xs[r][pos + 0] = v.x; xs[r][pos + 1] = v.y;
            xs[r][pos + 2] = v.z; xs[r][pos + 3] = v.w;
        }
        {
            int k = tid >> 3, pos = (tid & 7) << 2;
            *(float4*)&wsm[k][pos] = *(const float4*)&W1[(size_t)(kc * 32 + k) * H1C + pos];
        }
        __syncthreads();
        #pragma unroll
        for (int k = 0; k < 32; ++k) {
            float4 wv = *(const float4*)&wsm[k][tc << 2];
            float x0 = xs[tr][k], x1 = xs[tr + 32][k], x2 = xs[tr + 64][k], x3 = xs[tr + 96][k];
            accx[0] += x0 * wv.x; accy[0] += x0 * wv.y; accz[0] += x0 * wv.z; accw[0] += x0 * wv.w;
            accx[1] += x1 * wv.x; accy[1] += x1 * wv.y; accz[1] += x1 * wv.z; accw[1] += x1 * wv.w;
            accx[2] += x2 * wv.x; accy[2] += x2 * wv.y; accz[2] += x2 * wv.z; accw[2] += x2 * wv.w;
            accx[3] += x3 * wv.x; accy[3] += x3 * wv.y; accz[3] += x3 * wv.z; accw[3] += x3 * wv.w;
        }
    }
    #pragma unroll
    for (int i = 0; i < 4; ++i) {
        float4 v; v.x = accx[i]; v.y = accy[i]; v.z = accz[i]; v.w = accw[i];
        *(float4*)&h[(size_t)(rowbase + tr + 32 * i) * H1C + (tc << 2)] = v;
    }
}

__global__ void k_scatter1(const int* __restrict__ src, const int* __restrict__ dst,
                           const float* __restrict__ h, const float* __restrict__ dinv,
                           float* __restrict__ agg1) {
    int gid = blockIdx.x * 256 + threadIdx.x;
    int e = gid >> 5, f = gid & 31;
    int s = src[e], d = dst[e];
    float c = dinv[s] * dinv[d];
    unsafeAtomicAdd(&agg1[(d << 5) + f], h[(s << 5) + f] * c);
}

__global__ void k_h1(const float* __restrict__ agg1, const float* __restrict__ h,
                     const float* __restrict__ dinv, float* __restrict__ h1) {
    int i4 = blockIdx.x * 256 + threadIdx.x;
    int row = i4 >> 3;
    float di = dinv[row], d2 = di * di;
    float4 a = ((const float4*)agg1)[i4];
    float4 hv = ((const float4*)h)[i4];
    float4 r;
    r.x = fmaxf(a.x + hv.x * d2, 0.0f);
    r.y = fmaxf(a.y + hv.y * d2, 0.0f);
    r.z = fmaxf(a.z + hv.z * d2, 0.0f);
    r.w = fmaxf(a.w + hv.w * d2, 0.0f);
    ((float4*)h1)[i4] = r;
}

__global__ void k_gemm2(const float* __restrict__ h1, const float* __restrict__ W2,
                        const float* __restrict__ W3, float* __restrict__ h2mu,
                        float* __restrict__ h2lv) {
    __shared__ float w2s[H1C * H2C], w3s[H1C * H2C];
    int tid = threadIdx.x;
    for (int i = tid; i < H1C * H2C; i += 256) { w2s[i] = W2[i]; w3s[i] = W3[i]; }
    __syncthreads();
    int gid = blockIdx.x * 256 + tid;
    int row = gid >> 5, c = gid & 31, col = c & 15;
    const float* wsrc = (c & 16) ? w3s : w2s;
    const float* hr = &h1[(size_t)row << 5];
    float acc = 0.0f;
    #pragma unroll
    for (int k = 0; k < H1C; ++k) acc += hr[k] * wsrc[(k << 4) + col];
    if (c & 16) h2lv[(row << 4) + col] = acc;
    else        h2mu[(row << 4) + col] = acc;
}

__global__ void k_scatter2(const int* __restrict__ src, const int* __restrict__ dst,
                           const float* __restrict__ h2mu, const float* __restrict__ h2lv,
                           const float* __restrict__ dinv, float* __restrict__ aggmu,
                           float* __restrict__ agglv) {
    int gid = blockIdx.x * 256 + threadIdx.x;
    int e = gid >> 5, f = gid & 31;
    int s = src[e], d = dst[e];
    float c = dinv[s] * dinv[d];
    int ff = f & 15;
    if (f < 16) unsafeAtomicAdd(&aggmu[(d << 4) + ff], h2mu[(s << 4) + ff] * c);
    else        unsafeAtomicAdd(&agglv[(d << 4) + ff], h2lv[(s << 4) + ff] * c);
}

__global__ void k_zmu(const float* __restrict__ aggmu, const float* __restrict__ agglv,
                      const float* __restrict__ h2mu, const float* __restrict__ h2lv,
                      const float* __restrict__ dinv, const float* __restrict__ eps,
                      float* __restrict__ zbuf, float* __restrict__ out,
                      float* __restrict__ kldp) {
    int gid = blockIdx.x * 256 + threadIdx.x;
    int row = gid >> 4;
    float di = dinv[row], d2 = di * di;
    float m  = aggmu[gid] + h2mu[gid] * d2;
    float lv = agglv[gid] + h2lv[gid] * d2;
    float el = __expf(lv);
    float zv = eps[gid] * el + m;
    zbuf[gid] = zv;
    out[1 + gid] = m;
    float kt = 1.0f + 2.0f * lv - m * m - el * el;
    float bs = block_reduce_sum(kt, 256);
    if (threadIdx.x == 0) kldp[blockIdx.x] = bs;
}

// BCE: each block owns 128 cols x 256 rows (4 iters of 64 rows), 512 threads.
// zcT staged once; zrT double-buffered; adjacency for iter i+1 issued BEFORE
// computing iter i (fully unrolled -> y[2][4] stays in registers). Barrier at
// end of each iter makes the double-buffer race-free (writes to buf b at iter
// i are separated from reads of buf b at iter i-2 by barrier i-1).
__global__ void __launch_bounds__(512)
k_bce(const float* __restrict__ z, const int* __restrict__ adj,
      float* __restrict__ part) {
    __shared__ float zcT[16][132];       // 128 cols, transposed, padded
    __shared__ float zrT[2][16][68];     // 2 x 64 rows, transposed, padded
    int tid = threadIdx.x;
    int cbase = blockIdx.x << 7;         // 64 col-tiles
    int rbase0 = blockIdx.y << 8;        // 32 row-panels of 256 rows

    {
        int r = tid >> 2, kc = (tid & 3) << 2;
        float4 w = *(const float4*)&z[(size_t)(cbase + r) * H2C + kc];
        zcT[kc + 0][r] = w.x; zcT[kc + 1][r] = w.y; zcT[kc + 2][r] = w.z; zcT[kc + 3][r] = w.w;
        if (tid < 256) {
            float4 v = *(const float4*)&z[(size_t)(rbase0 + r) * H2C + kc];
            zrT[0][kc + 0][r] = v.x; zrT[0][kc + 1][r] = v.y;
            zrT[0][kc + 2][r] = v.z; zrT[0][kc + 3][r] = v.w;
        }
    }
    int tx = tid & 31, ty = tid >> 5;    // 32 col-groups x 16 row-groups, 4x4 each
    const int* abase = adj + (size_t)(rbase0 + (ty << 2)) * N_NODES + cbase + (tx << 2);

    int4 y[2][4];
    #pragma unroll
    for (int r = 0; r < 4; ++r)
        y[0][r] = *(const int4*)(abase + (size_t)r * N_NODES);
    __syncthreads();

    float lsum = 0.0f;
    #pragma unroll
    for (int it = 0; it < BCE_NITER; ++it) {
        const int cur = it & 1, nxt = cur ^ 1;
        if (it + 1 < BCE_NITER) {
            // prefetch next iter's adjacency (in flight through this iter's compute)
            const int* an = abase + (size_t)(it + 1) * 64 * N_NODES;
            #pragma unroll
            for (int r = 0; r < 4; ++r)
                y[nxt][r] = *(const int4*)(an + (size_t)r * N_NODES);
            // restage zrT for next iter (z is L2-resident)
            if (tid < 256) {
                int r = tid >> 2, kc = (tid & 3) << 2;
                float4 v = *(const float4*)&z[(size_t)(rbase0 + (it + 1) * 64 + r) * H2C + kc];
                zrT[nxt][kc + 0][r] = v.x; zrT[nxt][kc + 1][r] = v.y;
                zrT[nxt][kc + 2][r] = v.z; zrT[nxt][kc + 3][r] = v.w;
            }
        }

        float a[4][4];
        #pragma unroll
        for (int i = 0; i < 4; ++i)
            #pragma unroll
            for (int j = 0; j < 4; ++j) a[i][j] = 0.0f;

        #pragma unroll
        for (int k = 0; k < H2C; ++k) {
            float4 av = *(const float4*)&zrT[cur][k][ty << 2];
            float4 ac = *(const float4*)&zcT[k][tx << 2];
            a[0][0] += av.x * ac.x; a[0][1] += av.x * ac.y; a[0][2] += av.x * ac.z; a[0][3] += av.x * ac.w;
            a[1][0] += av.y * ac.x; a[1][1] += av.y * ac.y; a[1][2] += av.y * ac.z; a[1][3] += av.y * ac.w;
            a[2][0] += av.z * ac.x; a[2][1] += av.z * ac.y; a[2][2] += av.z * ac.z; a[2][3] += av.z * ac.w;
            a[3][0] += av.w * ac.x; a[3][1] += av.w * ac.y; a[3][2] += av.w * ac.z; a[3][3] += av.w * ac.w;
        }
        #pragma unroll
        for (int r = 0; r < 4; ++r) {
            int4 yv = y[cur][r];
            lsum += bce_elem(a[r][0], yv.x) + bce_elem(a[r][1], yv.y)
                  + bce_elem(a[r][2], yv.z) + bce_elem(a[r][3], yv.w);
        }
        if (it + 1 < BCE_NITER) __syncthreads();
    }

    float bs = block_reduce_sum(lsum, 512);
    if (tid == 0) part[blockIdx.y * gridDim.x + blockIdx.x] = bs;
}

__global__ void k_final(const float* __restrict__ part, const float* __restrict__ kldp,
                        const float* __restrict__ norm, float* __restrict__ out) {
    double s = 0.0, k = 0.0;
    for (int i = threadIdx.x; i < 2048; i += 256) s += (double)part[i];
    for (int i = threadIdx.x; i < 512; i += 256) k += (double)kldp[i];
    #pragma unroll
    for (int off = 32; off; off >>= 1) {
        s += __shfl_down(s, off, 64);
        k += __shfl_down(k, off, 64);
    }
    __shared__ double ss[4], kk[4];
    int lane = threadIdx.x & 63, wid = threadIdx.x >> 6;
    if (lane == 0) { ss[wid] = s; kk[wid] = k; }
    __syncthreads();
    if (threadIdx.x == 0) {
        double st = ss[0] + ss[1] + ss[2] + ss[3];
        double kt = kk[0] + kk[1] + kk[2] + kk[3];
        double bce = st / ((double)N_NODES * (double)N_NODES);
        double kld = (-0.5 / (double)N_NODES) * (kt / (double)N_NODES);
        out[0] = (float)((double)norm[0] * bce + kld);
    }
}

// ---------------- launch ----------------

extern "C" void kernel_launch(void* const* d_in, const int* in_sizes, int n_in,
                              void* d_out, int out_size, void* d_ws, size_t ws_size,
                              hipStream_t stream) {
    const float* x    = (const float*)d_in[0];
    const int*   ei   = (const int*)d_in[1];
    const int*   adj  = (const int*)d_in[2];
    const float* eps  = (const float*)d_in[3];
    const float* norm = (const float*)d_in[4];
    const float* W1   = (const float*)d_in[5];
    const float* W2   = (const float*)d_in[6];
    const float* W3   = (const float*)d_in[7];
    float* out = (float*)d_out;
    char*  ws  = (char*)d_ws;

    const int* src = ei;
    const int* dst = ei + N_EDGES;

    int*   deg    = (int*)  (ws + 0);
    float* dinv   = (float*)(ws + 32768);
    float* h      = (float*)(ws + 65536);
    float* agg1   = (float*)(ws + 1114112);
    float* h1     = (float*)(ws + 2162688);
    float* h2mu   = (float*)(ws + 3211264);
    float* h2lv   = (float*)(ws + 3735552);
    float* aggmu  = (float*)(ws + 4259840);
    float* agglv  = (float*)(ws + 4784128);   // contiguous after aggmu
    float* zbuf   = (float*)(ws + 5308416);
    float* part   = (float*)(ws + 5832704);   // 2048 f32
    float* kldp   = (float*)(ws + 5898240);   // 512 f32

    // zero deg + agg1 + aggmu/agglv without memset fill nodes (133120 float4)
    k_init<<<520, 256, 0, stream>>>((float4*)deg, (float4*)agg1, (float4*)aggmu);

    k_deg<<<N_EDGES / 256, 256, 0, stream>>>(dst, deg);
    k_dinv<<<N_NODES / 256, 256, 0, stream>>>(deg, dinv);
    k_gemm1<<<N_NODES / 128, 256, 0, stream>>>(x, W1, h);
    k_scatter1<<<(N_EDGES * 32) / 256, 256, 0, stream>>>(src, dst, h, dinv, agg1);
    k_h1<<<(N_NODES * H1C / 4) / 256, 256, 0, stream>>>(agg1, h, dinv, h1);
    k_gemm2<<<(N_NODES * 32) / 256, 256, 0, stream>>>(h1, W2, W3, h2mu, h2lv);
    k_scatter2<<<(N_EDGES * 32) / 256, 256, 0, stream>>>(src, dst, h2mu, h2lv, dinv, aggmu, agglv);
    k_zmu<<<(N_NODES * H2C) / 256, 256, 0, stream>>>(aggmu, agglv, h2mu, h2lv, dinv, eps, zbuf, out, kldp);
    k_bce<<<dim3(64, 32), 512, 0, stream>>>(zbuf, adj, part);
    k_final<<<1, 256, 0, stream>>>(part, kldp, norm, out);
}